// Round 15
// baseline (1031.832 us; speedup 1.0000x reference)
//
#include <hip/hip_runtime.h>

#define TT 4096
#define BB 128
#define L2E 1.4426950408889634f

typedef unsigned uv2 __attribute__((ext_vector_type(2)));
typedef float v2f __attribute__((ext_vector_type(2)));
typedef float v4f __attribute__((ext_vector_type(4)));
typedef __bf16 v8bf __attribute__((ext_vector_type(8)));

__device__ __forceinline__ float fexp2(float a) { return __builtin_amdgcn_exp2f(a); }

__device__ __forceinline__ float bpermf(int idx_bytes, float v) {
  return __int_as_float(__builtin_amdgcn_ds_bpermute(idx_bytes, __float_as_int(v)));
}

// (fallback kernel only)
__device__ __forceinline__ float xhalf_sum(float p) {
#if __has_builtin(__builtin_amdgcn_permlane32_swap)
  uv2 r = __builtin_amdgcn_permlane32_swap(__float_as_uint(p), __float_as_uint(p),
                                           false, false);
  return __uint_as_float(r[0]) + __uint_as_float(r[1]);
#else
  return p + bpermf((threadIdx.x ^ 32) << 2, p);
#endif
}

// pack two f32 -> 2xbf16 dword (RNE)
__device__ __forceinline__ unsigned cvtpk(float lo, float hi) {
  unsigned r;
  asm("v_cvt_pk_bf16_f32 %0, %1, %2" : "=v"(r) : "v"(lo), "v"(hi));
  return r;
}

__device__ __forceinline__ v8bf frag_from(unsigned u0, unsigned u1, unsigned u2,
                                          unsigned u3) {
  uint4 uu = make_uint4(u0, u1, u2, u3);
  return __builtin_bit_cast(v8bf, uu);
}

// gx[b,t,g]: g<64  -> L2E*(x.w_ih[g] + b_ih[g] + b_hh[g])   (r,z pre-activation)
//            g>=64 -> 2*L2E*(x.w_ih[g] + b_ih[g])           (n x-side)
__global__ __launch_bounds__(256) void gx_pre(
    const float* __restrict__ x, const float* __restrict__ w_ih,
    const float* __restrict__ b_ih, const float* __restrict__ b_hh,
    const int* __restrict__ lengths, float* __restrict__ gx) {
  const size_t idx = (size_t)blockIdx.x * 256 + threadIdx.x;  // (b*T+t)*96+g
  const int g = (int)(idx % 96);
  const size_t bt = idx / 96;
  const int b = (int)(bt >> 12);
  const int t = (int)(bt & (TT - 1));
  if (t >= lengths[b]) return;
  const float* xp = x + bt * 6;
  float acc = (g < 64) ? (b_ih[g] + b_hh[g]) : b_ih[g];
#pragma unroll
  for (int i = 0; i < 6; ++i) acc = fmaf(w_ih[g * 6 + i], xp[i], acc);
  gx[idx] = (g < 64) ? (L2E * acc) : (2.0f * L2E * acc);
}

// TRANSPOSED-MFMA GRU. One wave per batch element.
// D = A.B with A = W permuted (6 constant frags), B = h (k-distributed frag).
// Lane l (g=l>>4, n=l&15, q=n&3): frag-a reg i = y[8g+i], frag-b reg i =
// y[8g+4+i] (π(m)=8(m>>2)+(m&3) baked into A rows; D row=(l>>4)*4+reg, m89).
// Lane runs the gate tail for rows 8g+2q, 8g+2q+1 only (fp32 recurrence for
// its 2 rows); next B-frag assembled via cvt_pk + 4 quad_perm DPP broadcasts
// (VALU) — NO LDS gather in the loop.
__global__ __launch_bounds__(64) __attribute__((amdgpu_waves_per_eu(1, 1)))
void gru_seq(const int* __restrict__ lengths, const float* __restrict__ w_hh,
             const float* __restrict__ b_hh, const float* __restrict__ gx,
             float* __restrict__ hbuf) {
  __shared__ alignas(16) float hring[2][32][32];  // buf, step, j = 8 KB

  const int b = blockIdx.x;
  const int l = threadIdx.x;
  const int g = l >> 4;
  const int n_ = l & 15;
  const int q = n_ & 3;
  const int kb = g * 8;        // this lane's k-octet base (A and B k-map)
  const int row0 = kb + 2 * q; // first of the 2 gate-rows this lane owns
  const int len = lengths[b];

  // constant A fragments: A[m=n_][k=kb+e] = W[grow + pi(n_) + (+4 for b)][k]*scale
  auto make_wfragA = [&](int grow, int plus4, float scale) -> v8bf {
    const int prow = 8 * (n_ >> 2) + (n_ & 3) + plus4;
    const float* wrow = w_hh + (grow + prow) * 32 + kb;
    unsigned u0 = cvtpk(wrow[0] * scale, wrow[1] * scale);
    unsigned u1 = cvtpk(wrow[2] * scale, wrow[3] * scale);
    unsigned u2 = cvtpk(wrow[4] * scale, wrow[5] * scale);
    unsigned u3 = cvtpk(wrow[6] * scale, wrow[7] * scale);
    return frag_from(u0, u1, u2, u3);
  };
  const v8bf fRa = make_wfragA(0, 0, L2E),  fRb = make_wfragA(0, 4, L2E);
  const v8bf fZa = make_wfragA(32, 0, L2E), fZb = make_wfragA(32, 4, L2E);
  const v8bf fNa = make_wfragA(64, 0, 2.0f * L2E), fNb = make_wfragA(64, 4, 2.0f * L2E);
  // n-gate hidden bias as C: reg i of frag a must be bhn[8g+i], frag b bhn[8g+4+i]
  v4f cna, cnb;
#pragma unroll
  for (int i = 0; i < 4; ++i) {
    cna[i] = 2.0f * L2E * b_hh[64 + kb + i];
    cnb[i] = 2.0f * L2E * b_hh[64 + kb + 4 + i];
  }
  const v4f zero4 = v4f{0.f, 0.f, 0.f, 0.f};
  const bool c1 = (q & 1) != 0;
  const bool c2 = (q & 2) != 0;

  const float* gxb = gx + (size_t)b * TT * 96;
  float* hrow = hbuf + (size_t)b * TT * 32;

  // state: this lane's 2 fp32 h rows + the shared bf16 B-fragment
  float h0 = 0.f, h1 = 0.f;
  v8bf hb = frag_from(0u, 0u, 0u, 0u);

  int t = 0;

  // 4-deep gx prefetch slots: per step (xr0,xr1,xz0,xz1,xn0,xn1) for rows row0,row0+1
  float s0a, s0b, s0c, s0d, s0e, s0f;
  float s1a, s1b, s1c, s1d, s1e, s1f;
  float s2a, s2b, s2c, s2d, s2e, s2f;
  float s3a, s3b, s3c, s3d, s3e, s3f;
  {
    const int t1 = (1 < len) ? 1 : len - 1, t2 = (2 < len) ? 2 : len - 1,
              t3 = (3 < len) ? 3 : len - 1;
    const float *p0 = gxb, *p1 = gxb + (size_t)t1 * 96,
                *p2 = gxb + (size_t)t2 * 96, *p3 = gxb + (size_t)t3 * 96;
    s0a = p0[row0]; s0b = p0[row0 + 1]; s0c = p0[32 + row0]; s0d = p0[33 + row0];
    s0e = p0[64 + row0]; s0f = p0[65 + row0];
    s1a = p1[row0]; s1b = p1[row0 + 1]; s1c = p1[32 + row0]; s1d = p1[33 + row0];
    s1e = p1[64 + row0]; s1f = p1[65 + row0];
    s2a = p2[row0]; s2b = p2[row0 + 1]; s2c = p2[32 + row0]; s2d = p2[33 + row0];
    s2e = p2[64 + row0]; s2f = p2[65 + row0];
    s3a = p3[row0]; s3b = p3[row0 + 1]; s3c = p3[32 + row0]; s3d = p3[33 + row0];
    s3e = p3[64 + row0]; s3f = p3[65 + row0];
  }

  auto flush = [&](int base, int cnt) {
    const float4* src = (const float4*)(&hring[(base >> 5) & 1][0][0]);
    float4* dst = (float4*)(hrow + (size_t)base * 32);
    const int n4 = cnt * 8;
    for (int qq = l; qq < n4; qq += 64) dst[qq] = src[qq];
  };

  // select this lane's 2 rows (2q, 2q+1) from the frag pair (hoisted masks)
  auto sel2 = [&](v4f fa, v4f fb, float& y0, float& y1) {
    const float a0 = c1 ? fa[2] : fa[0], a1 = c1 ? fa[3] : fa[1];
    const float b0 = c1 ? fb[2] : fb[0], b1 = c1 ? fb[3] : fb[1];
    y0 = c2 ? b0 : a0;
    y1 = c2 ? b1 : a1;
  };

  auto step = [&](float& XR0, float& XR1, float& XZ0, float& XZ1, float& XN0,
                  float& XN1) {
    const float xr0 = XR0, xr1 = XR1, xz0 = XZ0, xz1 = XZ1, xn0 = XN0, xn1 = XN1;
    // refill this slot for t+4
    {
      const int tp = (t + 4 < len) ? (t + 4) : (len - 1);
      const float* gp = gxb + (size_t)tp * 96;
      XR0 = gp[row0]; XR1 = gp[row0 + 1];
      XZ0 = gp[32 + row0]; XZ1 = gp[33 + row0];
      XN0 = gp[64 + row0]; XN1 = gp[65 + row0];
    }

    // 6 independent MFMAs: y[m] = (W.h)[pi-rows], replicated over cols
    const v4f yra = __builtin_amdgcn_mfma_f32_16x16x32_bf16(fRa, hb, zero4, 0, 0, 0);
    const v4f yrb = __builtin_amdgcn_mfma_f32_16x16x32_bf16(fRb, hb, zero4, 0, 0, 0);
    const v4f yza = __builtin_amdgcn_mfma_f32_16x16x32_bf16(fZa, hb, zero4, 0, 0, 0);
    const v4f yzb = __builtin_amdgcn_mfma_f32_16x16x32_bf16(fZb, hb, zero4, 0, 0, 0);
    const v4f yna = __builtin_amdgcn_mfma_f32_16x16x32_bf16(fNa, hb, cna, 0, 0, 0);
    const v4f ynb = __builtin_amdgcn_mfma_f32_16x16x32_bf16(fNb, hb, cnb, 0, 0, 0);

    float yr0, yr1, yz0, yz1, hn0, hn1;
    sel2(yra, yrb, yr0, yr1);
    sel2(yza, yzb, yz0, yz1);
    sel2(yna, ynb, hn0, hn1);

    // 2 independent gate tails (fp32), rows row0, row0+1
    const float r0 = __builtin_amdgcn_rcpf(1.0f + fexp2(-(yr0 + xr0)));
    const float r1 = __builtin_amdgcn_rcpf(1.0f + fexp2(-(yr1 + xr1)));
    const float z0 = __builtin_amdgcn_rcpf(1.0f + fexp2(-(yz0 + xz0)));
    const float z1 = __builtin_amdgcn_rcpf(1.0f + fexp2(-(yz1 + xz1)));
    const float ap0 = fmaf(r0, hn0, xn0);
    const float ap1 = fmaf(r1, hn1, xn1);
    const float q0 = __builtin_amdgcn_rcpf(1.0f + fexp2(-ap0));
    const float q1 = __builtin_amdgcn_rcpf(1.0f + fexp2(-ap1));
    const float nn0 = fmaf(2.0f, q0, -1.0f);
    const float nn1 = fmaf(2.0f, q1, -1.0f);
    h0 = fmaf(z0, h0 - nn0, nn0);
    h1 = fmaf(z1, h1 - nn1, nn1);

    // rebuild B-frag: own bf16 pair + 3 quad neighbors via DPP broadcasts
    const int dw = (int)cvtpk(h0, h1);
    const int u0 = __builtin_amdgcn_update_dpp(0, dw, 0x00, 0xF, 0xF, true);
    const int u1 = __builtin_amdgcn_update_dpp(0, dw, 0x55, 0xF, 0xF, true);
    const int u2 = __builtin_amdgcn_update_dpp(0, dw, 0xAA, 0xF, 0xF, true);
    const int u3 = __builtin_amdgcn_update_dpp(0, dw, 0xFF, 0xF, 0xF, true);
    hb = frag_from((unsigned)u0, (unsigned)u1, (unsigned)u2, (unsigned)u3);

    // h history: duplicate lanes (same g,q) write identical values
    *(float2*)(&hring[(t >> 5) & 1][t & 31][row0]) = make_float2(h0, h1);
    if ((t & 31) == 31) flush(t - 31, 32);
    ++t;
  };

  while (t + 4 <= len) {
    step(s0a, s0b, s0c, s0d, s0e, s0f);
    step(s1a, s1b, s1c, s1d, s1e, s1f);
    step(s2a, s2b, s2c, s2d, s2e, s2f);
    step(s3a, s3b, s3c, s3d, s3e, s3f);
  }
  if (t < len) step(s0a, s0b, s0c, s0d, s0e, s0f);
  if (t < len) step(s1a, s1b, s1c, s1d, s1e, s1f);
  if (t < len) step(s2a, s2b, s2c, s2d, s2e, s2f);

  const int rem = len & 31;
  if (rem) flush(len - rem, rem);
}

// out[b,t,:] = (t < len[b]) ? h[b,t,:] @ fc_w^T + fc_b : fc_b
__global__ __launch_bounds__(256) void fc_apply(
    const float* __restrict__ hbuf, const int* __restrict__ lengths,
    const float* __restrict__ fc_w, const float* __restrict__ fc_b,
    float* __restrict__ out) {
  const int idx = blockIdx.x * 256 + threadIdx.x;  // flattened (b,t)
  const int b = idx >> 12;
  const int t = idx & (TT - 1);
  const float fb0 = fc_b[0], fb1 = fc_b[1];
  float* op = out + (size_t)idx * 2;
  if (t >= lengths[b]) {
    op[0] = fb0;
    op[1] = fb1;
    return;
  }
  const float4* hp = (const float4*)(hbuf + (size_t)idx * 32);
  const float4* w0 = (const float4*)(fc_w);
  const float4* w1 = (const float4*)(fc_w + 32);
  float o0 = 0.f, o1 = 0.f;
#pragma unroll
  for (int qq = 0; qq < 8; ++qq) {
    const float4 hv = hp[qq], a = w0[qq], c = w1[qq];
    o0 += hv.x * a.x + hv.y * a.y + hv.z * a.z + hv.w * a.w;
    o1 += hv.x * c.x + hv.y * c.y + hv.z * c.z + hv.w * c.w;
  }
  op[0] = o0 + fb0;
  op[1] = o1 + fb1;
}

// Fallback (ws too small): self-contained single kernel (R6 structure).
__global__ __launch_bounds__(64) void gru_fallback(
    const float* __restrict__ x, const int* __restrict__ lengths,
    const float* __restrict__ w_ih, const float* __restrict__ w_hh,
    const float* __restrict__ b_ih, const float* __restrict__ b_hh,
    const float* __restrict__ fc_w, const float* __restrict__ fc_b,
    float* __restrict__ out) {
  const int b = blockIdx.x;
  const int l = threadIdx.x;
  const int j = l & 31;
  const int half = l >> 5;
  const int ko = half << 4;
  const int len = lengths[b];

  float wr[16], wz[16], wn[16];
#pragma unroll
  for (int k = 0; k < 16; ++k) wr[k] = w_hh[j * 32 + ko + k] * L2E;
#pragma unroll
  for (int k = 0; k < 16; ++k) wz[k] = w_hh[(32 + j) * 32 + ko + k] * L2E;
#pragma unroll
  for (int k = 0; k < 16; ++k) wn[k] = w_hh[(64 + j) * 32 + ko + k] * (2.0f * L2E);
  float wxr[6], wxz[6], wxn[6];
#pragma unroll
  for (int i = 0; i < 6; ++i) wxr[i] = w_ih[j * 6 + i] * (0.5f * L2E);
#pragma unroll
  for (int i = 0; i < 6; ++i) wxz[i] = w_ih[(32 + j) * 6 + i] * (0.5f * L2E);
#pragma unroll
  for (int i = 0; i < 6; ++i) wxn[i] = w_ih[(64 + j) * 6 + i] * (2.0f * L2E);
  const float br = (b_ih[j] + b_hh[j]) * (0.5f * L2E);
  const float bz = (b_ih[32 + j] + b_hh[32 + j]) * (0.5f * L2E);
  const float bxn = b_ih[64 + j] * (2.0f * L2E);
  const float bhn = b_hh[64 + j] * L2E;
  const float fcw = fc_w[half * 32 + j];
  const float fcb = fc_b[half];

  const float* xb = x + (size_t)b * (TT * 6);
  float* ob = out + (size_t)b * (TT * 2);
  const int bko = half << 6;
  float h = 0.0f;

  v2f cx[3], nx[3];
  {
    const v2f* xp = (const v2f*)xb;
    cx[0] = xp[0]; cx[1] = xp[1]; cx[2] = xp[2];
  }
  for (int t = 0; t < len; ++t) {
    const int tn = (t + 1 < len) ? (t + 1) : t;
    const v2f* xp = (const v2f*)(xb + tn * 6);
    nx[0] = xp[0]; nx[1] = xp[1]; nx[2] = xp[2];
    float xr = br, xz = bz, xn = bxn;
#pragma unroll
    for (int i = 0; i < 3; ++i) {
      const float c0 = cx[i][0], c1 = cx[i][1];
      xr = fmaf(wxr[2 * i], c0, xr); xr = fmaf(wxr[2 * i + 1], c1, xr);
      xz = fmaf(wxz[2 * i], c0, xz); xz = fmaf(wxz[2 * i + 1], c1, xz);
      xn = fmaf(wxn[2 * i], c0, xn); xn = fmaf(wxn[2 * i + 1], c1, xn);
    }
    float hbv[16];
#pragma unroll
    for (int k = 0; k < 16; ++k) hbv[k] = bpermf(bko + (k << 2), h);
    float ar0 = xr, ar1 = 0.f, az0 = xz, az1 = 0.f, an0 = bhn, an1 = 0.f;
#pragma unroll
    for (int k = 0; k < 8; ++k) {
      ar0 = fmaf(wr[k], hbv[k], ar0);
      ar1 = fmaf(wr[k + 8], hbv[k + 8], ar1);
      az0 = fmaf(wz[k], hbv[k], az0);
      az1 = fmaf(wz[k + 8], hbv[k + 8], az1);
      an0 = fmaf(wn[k], hbv[k], an0);
      an1 = fmaf(wn[k + 8], hbv[k + 8], an1);
    }
    const float sr = xhalf_sum(ar0 + ar1);
    const float r = __builtin_amdgcn_rcpf(1.0f + fexp2(-sr));
    const float sz = xhalf_sum(az0 + az1);
    const float z = __builtin_amdgcn_rcpf(1.0f + fexp2(-sz));
    const float hn = xhalf_sum(an0 + an1);
    const float ap = fmaf(r, hn, xn);
    const float qq = __builtin_amdgcn_rcpf(1.0f + fexp2(-ap));
    const float nn = fmaf(2.0f, qq, -1.0f);
    h = fmaf(z, h - nn, nn);
    float p = h * fcw;
    p += __shfl_xor(p, 1);
    p += __shfl_xor(p, 2);
    p += __shfl_xor(p, 4);
    p += __shfl_xor(p, 8);
    p += __shfl_xor(p, 16);
    if (j == 0) ob[t * 2 + half] = p + fcb;
#pragma unroll
    for (int i = 0; i < 3; ++i) cx[i] = nx[i];
  }
  const float fb0 = fc_b[0], fb1 = fc_b[1];
  for (int idx = len * 2 + l; idx < TT * 2; idx += 64)
    ob[idx] = (idx & 1) ? fb1 : fb0;
}

extern "C" void kernel_launch(void* const* d_in, const int* in_sizes, int n_in,
                              void* d_out, int out_size, void* d_ws, size_t ws_size,
                              hipStream_t stream) {
  const float* x       = (const float*)d_in[0];
  const int*   lengths = (const int*)d_in[1];
  const float* w_ih    = (const float*)d_in[2];
  const float* w_hh    = (const float*)d_in[3];
  const float* b_ih    = (const float*)d_in[4];
  const float* b_hh    = (const float*)d_in[5];
  const float* fc_w    = (const float*)d_in[6];
  const float* fc_b    = (const float*)d_in[7];
  float* outp = (float*)d_out;

  const size_t hbuf_elems = (size_t)BB * TT * 32;               // 64 MB
  const size_t gx_elems   = (size_t)BB * TT * 96;               // 192 MB
  const size_t need = (hbuf_elems + gx_elems) * sizeof(float);  // 256 MB
  if (ws_size >= need) {
    float* hbuf = (float*)d_ws;
    float* gx = (float*)d_ws + hbuf_elems;
    hipLaunchKernelGGL(gx_pre, dim3((BB * TT * 96) / 256), dim3(256), 0, stream,
                       x, w_ih, b_ih, b_hh, lengths, gx);
    hipLaunchKernelGGL(gru_seq, dim3(BB), dim3(64), 0, stream,
                       lengths, w_hh, b_hh, gx, hbuf);
    hipLaunchKernelGGL(fc_apply, dim3((BB * TT) / 256), dim3(256), 0, stream,
                       hbuf, lengths, fc_w, fc_b, outp);
  } else {
    hipLaunchKernelGGL(gru_fallback, dim3(BB), dim3(64), 0, stream,
                       x, lengths, w_ih, w_hh, b_ih, b_hh, fc_w, fc_b, outp);
  }
}

// Round 17
// 869.694 us; speedup vs baseline: 1.1864x; 1.1864x over previous
//
#include <hip/hip_runtime.h>

#define TT 4096
#define BB 128
#define L2E 1.4426950408889634f

typedef unsigned uv2 __attribute__((ext_vector_type(2)));
typedef float v2f __attribute__((ext_vector_type(2)));
typedef float v4f __attribute__((ext_vector_type(4)));
typedef __bf16 v8bf __attribute__((ext_vector_type(8)));

__device__ __forceinline__ float fexp2(float a) { return __builtin_amdgcn_exp2f(a); }

__device__ __forceinline__ float bpermf(int idx_bytes, float v) {
  return __int_as_float(__builtin_amdgcn_ds_bpermute(idx_bytes, __float_as_int(v)));
}

// (fallback kernel only)
__device__ __forceinline__ float xhalf_sum(float p) {
#if __has_builtin(__builtin_amdgcn_permlane32_swap)
  uv2 r = __builtin_amdgcn_permlane32_swap(__float_as_uint(p), __float_as_uint(p),
                                           false, false);
  return __uint_as_float(r[0]) + __uint_as_float(r[1]);
#else
  return p + bpermf((threadIdx.x ^ 32) << 2, p);
#endif
}

// pack two f32 -> 2xbf16 dword (RNE)
__device__ __forceinline__ unsigned cvtpk(float lo, float hi) {
  unsigned r;
  asm("v_cvt_pk_bf16_f32 %0, %1, %2" : "=v"(r) : "v"(lo), "v"(hi));
  return r;
}

template <int CTRL>
__device__ __forceinline__ int dppmv(int src) {
  return __builtin_amdgcn_update_dpp(0, src, CTRL, 0xF, 0xF, true);
}

__device__ __forceinline__ v8bf frag_from(unsigned u0, unsigned u1, unsigned u2,
                                          unsigned u3) {
  uint4 uu = make_uint4(u0, u1, u2, u3);
  return __builtin_bit_cast(v8bf, uu);
}

// gx[b,t,g]: g<64  -> L2E*(x.w_ih[g] + b_ih[g] + b_hh[g])   (r,z pre-activation)
//            g>=64 -> 2*L2E*(x.w_ih[g] + b_ih[g])           (n x-side)
__global__ __launch_bounds__(256) void gx_pre(
    const float* __restrict__ x, const float* __restrict__ w_ih,
    const float* __restrict__ b_ih, const float* __restrict__ b_hh,
    const int* __restrict__ lengths, float* __restrict__ gx) {
  const size_t idx = (size_t)blockIdx.x * 256 + threadIdx.x;  // (b*T+t)*96+g
  const int g = (int)(idx % 96);
  const size_t bt = idx / 96;
  const int b = (int)(bt >> 12);
  const int t = (int)(bt & (TT - 1));
  if (t >= lengths[b]) return;
  const float* xp = x + bt * 6;
  float acc = (g < 64) ? (b_ih[g] + b_hh[g]) : b_ih[g];
#pragma unroll
  for (int i = 0; i < 6; ++i) acc = fmaf(w_ih[g * 6 + i], xp[i], acc);
  gx[idx] = (g < 64) ? (L2E * acc) : (2.0f * L2E * acc);
}

// MFMA GRU, R14 structure with in-row DPP gather (no LDS on the serial chain).
// k-map CHOICE: lane group g covers k-octet koff(g) = 16*(g&1) + 8*(g>>1)
// (octets 0,16,8,24). With tail row j = l&31, each 16-lane row holds exactly
// the h-octet it needs -> A-frag rebuilt via quad_perm/cvt_pk/row_ror DPP
// (VALU) instead of 8 ds_bpermute (LDS window). B-frags use the same k-map,
// so the k-sum is invariant. D col = lane&15 (m89) -> lane j gets y[j].
// row_ror:n semantics (GCN reduction pattern, GPUOpen/LLVM): dest[i] =
// src[(i-n)&15], so rotation s delivers quad (q-s)'s dword to quad q ->
// shift to fetch quad qb's dword at quad q_ is s = (q_ - qb) & 3.
// (R16 bug: signs were flipped -> wrong quads -> absmax 0.114.)
__global__ __launch_bounds__(64) __attribute__((amdgpu_waves_per_eu(1, 1)))
void gru_seq(const int* __restrict__ lengths, const float* __restrict__ w_hh,
             const float* __restrict__ b_hh, const float* __restrict__ gx,
             float* __restrict__ hbuf) {
  __shared__ alignas(16) float hring[2][32][32];  // buf, step, j = 8 KB

  const int b = blockIdx.x;
  const int l = threadIdx.x;
  const int j = l & 31;
  const int len = lengths[b];
  const int n_ = l & 15;                       // B/D column this lane carries
  const int g = l >> 4;                        // 16-lane row index
  const int koff = 16 * (g & 1) + 8 * (g >> 1);  // this row's k-octet base

  // selection indices for the DPP gather (hoisted to masks by the compiler)
  const int q_ = (l >> 2) & 3;                 // quad within the 16-row
  const int qb = 2 * (l >> 5);                 // first quad holding our octet
  const int s0 = (q_ - qb) & 3;                // rotation for dwords 0,1 (FIXED)
  const int s1 = (q_ - qb - 1) & 3;            // rotation for dwords 2,3 (FIXED)
  const bool s0a = s0 & 1, s0b = s0 & 2;
  const bool s1a = s1 & 1, s1b = s1 & 2;

  // 6 constant B fragments: B[k=koff+e][n] = W[grow + jb + n][koff+e] * scale
  auto make_wfrag = [&](int grow, int jb, float scale) -> v8bf {
    const float* wrow = w_hh + (grow + jb + n_) * 32 + koff;
    unsigned u0 = cvtpk(wrow[0] * scale, wrow[1] * scale);
    unsigned u1 = cvtpk(wrow[2] * scale, wrow[3] * scale);
    unsigned u2 = cvtpk(wrow[4] * scale, wrow[5] * scale);
    unsigned u3 = cvtpk(wrow[6] * scale, wrow[7] * scale);
    return frag_from(u0, u1, u2, u3);
  };
  const v8bf fR0 = make_wfrag(0, 0, L2E),          fR1 = make_wfrag(0, 16, L2E);
  const v8bf fZ0 = make_wfrag(32, 0, L2E),         fZ1 = make_wfrag(32, 16, L2E);
  const v8bf fN0 = make_wfrag(64, 0, 2.0f * L2E),  fN1 = make_wfrag(64, 16, 2.0f * L2E);
  v4f cn0, cn1;
  {
    const float c0 = 2.0f * L2E * b_hh[64 + n_];
    const float c1 = 2.0f * L2E * b_hh[80 + n_];
    cn0 = v4f{c0, c0, c0, c0};
    cn1 = v4f{c1, c1, c1, c1};
  }
  const v4f zero4 = v4f{0.f, 0.f, 0.f, 0.f};
  const bool hiSel = (g & 1);  // j >= 16 <=> use jb=16 fragment

  const float* gxb = gx + (size_t)b * TT * 96;
  float* hrow = hbuf + (size_t)b * TT * 32;

  float h = 0.0f;
  int t = 0;

  // 4-deep gx prefetch slots (named scalars; static indexing)
  float g0r, g0z, g0n, g1r, g1z, g1n, g2r, g2z, g2n, g3r, g3z, g3n;
  {
    const int t1 = (1 < len) ? 1 : len - 1, t2 = (2 < len) ? 2 : len - 1,
              t3 = (3 < len) ? 3 : len - 1;
    const float *p0 = gxb, *p1 = gxb + (size_t)t1 * 96,
                *p2 = gxb + (size_t)t2 * 96, *p3 = gxb + (size_t)t3 * 96;
    g0r = p0[j]; g0z = p0[32 + j]; g0n = p0[64 + j];
    g1r = p1[j]; g1z = p1[32 + j]; g1n = p1[64 + j];
    g2r = p2[j]; g2z = p2[32 + j]; g2n = p2[64 + j];
    g3r = p3[j]; g3z = p3[32 + j]; g3n = p3[64 + j];
  }

  auto flush = [&](int base, int cnt) {
    const float4* src = (const float4*)(&hring[(base >> 5) & 1][0][0]);
    float4* dst = (float4*)(hrow + (size_t)base * 32);
    const int n4 = cnt * 8;
    for (int qq = l; qq < n4; qq += 64) dst[qq] = src[qq];
  };

  auto step = [&](float& GR, float& GZ, float& GN) {
    const float xr_ = GR, xz_ = GZ, xn_ = GN;
    // refill this slot for t+4 (independent; max slack)
    {
      const int tp = (t + 4 < len) ? (t + 4) : (len - 1);
      const float* gp = gxb + (size_t)tp * 96;
      GR = gp[j]; GZ = gp[32 + j]; GN = gp[64 + j];
    }

    // ---- A-frag rebuild: pure DPP/VALU, all within this lane's 16-row ----
    // quad broadcasts of h: position 4q+0..3 of the row
    const int hi_ = __float_as_int(h);
    const int qa = dppmv<0x00>(hi_), qbv = dppmv<0x55>(hi_);
    const int qc = dppmv<0xAA>(hi_), qd = dppmv<0xFF>(hi_);
    // pair dwords held by quad q: u0 = pair(4q,4q+1), u1 = pair(4q+2,4q+3)
    const unsigned u0 = cvtpk(__int_as_float(qa), __int_as_float(qbv));
    const unsigned u1 = cvtpk(__int_as_float(qc), __int_as_float(qd));
    // rotations: ror(4s) at quad q delivers quad (q-s)'s dword
    const int r4u0 = dppmv<0x124>((int)u0), r8u0 = dppmv<0x128>((int)u0),
              r12u0 = dppmv<0x12C>((int)u0);
    const int r4u1 = dppmv<0x124>((int)u1), r8u1 = dppmv<0x128>((int)u1),
              r12u1 = dppmv<0x12C>((int)u1);
    // select the two quads (qb, qb+1) that hold our octet's 4 pair-dwords
    const unsigned d0 = s0b ? (s0a ? (unsigned)r12u0 : (unsigned)r8u0)
                            : (s0a ? (unsigned)r4u0 : u0);
    const unsigned d1 = s0b ? (s0a ? (unsigned)r12u1 : (unsigned)r8u1)
                            : (s0a ? (unsigned)r4u1 : u1);
    const unsigned d2 = s1b ? (s1a ? (unsigned)r12u0 : (unsigned)r8u0)
                            : (s1a ? (unsigned)r4u0 : u0);
    const unsigned d3 = s1b ? (s1a ? (unsigned)r12u1 : (unsigned)r8u1)
                            : (s1a ? (unsigned)r4u1 : u1);
    const v8bf ha = frag_from(d0, d1, d2, d3);

    // 6 independent MFMAs: full K=32 dot per gate-half
    const v4f yr0 = __builtin_amdgcn_mfma_f32_16x16x32_bf16(ha, fR0, zero4, 0, 0, 0);
    const v4f yr1 = __builtin_amdgcn_mfma_f32_16x16x32_bf16(ha, fR1, zero4, 0, 0, 0);
    const v4f yz0 = __builtin_amdgcn_mfma_f32_16x16x32_bf16(ha, fZ0, zero4, 0, 0, 0);
    const v4f yz1 = __builtin_amdgcn_mfma_f32_16x16x32_bf16(ha, fZ1, zero4, 0, 0, 0);
    const v4f yn0 = __builtin_amdgcn_mfma_f32_16x16x32_bf16(ha, fN0, cn0, 0, 0, 0);
    const v4f yn1 = __builtin_amdgcn_mfma_f32_16x16x32_bf16(ha, fN1, cn1, 0, 0, 0);

    const float yr = hiSel ? yr1[0] : yr0[0];
    const float yz = hiSel ? yz1[0] : yz0[0];
    const float hn = hiSel ? yn1[0] : yn0[0];  // incl. bhn via C

    const float r_ = __builtin_amdgcn_rcpf(1.0f + fexp2(-(yr + xr_)));
    const float z_ = __builtin_amdgcn_rcpf(1.0f + fexp2(-(yz + xz_)));
    const float ap = fmaf(r_, hn, xn_);
    const float q0 = __builtin_amdgcn_rcpf(1.0f + fexp2(-ap));
    const float nn = fmaf(2.0f, q0, -1.0f);
    h = fmaf(z_, h - nn, nn);

    hring[(t >> 5) & 1][t & 31][j] = h;  // duplicate halves write same value
    if ((t & 31) == 31) flush(t - 31, 32);
    ++t;
  };

  while (t + 4 <= len) {
    step(g0r, g0z, g0n);
    step(g1r, g1z, g1n);
    step(g2r, g2z, g2n);
    step(g3r, g3z, g3n);
  }
  if (t < len) step(g0r, g0z, g0n);
  if (t < len) step(g1r, g1z, g1n);
  if (t < len) step(g2r, g2z, g2n);

  const int rem = len & 31;
  if (rem) flush(len - rem, rem);
}

// out[b,t,:] = (t < len[b]) ? h[b,t,:] @ fc_w^T + fc_b : fc_b
__global__ __launch_bounds__(256) void fc_apply(
    const float* __restrict__ hbuf, const int* __restrict__ lengths,
    const float* __restrict__ fc_w, const float* __restrict__ fc_b,
    float* __restrict__ out) {
  const int idx = blockIdx.x * 256 + threadIdx.x;  // flattened (b,t)
  const int b = idx >> 12;
  const int t = idx & (TT - 1);
  const float fb0 = fc_b[0], fb1 = fc_b[1];
  float* op = out + (size_t)idx * 2;
  if (t >= lengths[b]) {
    op[0] = fb0;
    op[1] = fb1;
    return;
  }
  const float4* hp = (const float4*)(hbuf + (size_t)idx * 32);
  const float4* w0 = (const float4*)(fc_w);
  const float4* w1 = (const float4*)(fc_w + 32);
  float o0 = 0.f, o1 = 0.f;
#pragma unroll
  for (int qq = 0; qq < 8; ++qq) {
    const float4 hv = hp[qq], a = w0[qq], c = w1[qq];
    o0 += hv.x * a.x + hv.y * a.y + hv.z * a.z + hv.w * a.w;
    o1 += hv.x * c.x + hv.y * c.y + hv.z * c.z + hv.w * c.w;
  }
  op[0] = o0 + fb0;
  op[1] = o1 + fb1;
}

// Fallback (ws too small): self-contained single kernel (R6 structure).
__global__ __launch_bounds__(64) void gru_fallback(
    const float* __restrict__ x, const int* __restrict__ lengths,
    const float* __restrict__ w_ih, const float* __restrict__ w_hh,
    const float* __restrict__ b_ih, const float* __restrict__ b_hh,
    const float* __restrict__ fc_w, const float* __restrict__ fc_b,
    float* __restrict__ out) {
  const int b = blockIdx.x;
  const int l = threadIdx.x;
  const int j = l & 31;
  const int half = l >> 5;
  const int ko = half << 4;
  const int len = lengths[b];

  float wr[16], wz[16], wn[16];
#pragma unroll
  for (int k = 0; k < 16; ++k) wr[k] = w_hh[j * 32 + ko + k] * L2E;
#pragma unroll
  for (int k = 0; k < 16; ++k) wz[k] = w_hh[(32 + j) * 32 + ko + k] * L2E;
#pragma unroll
  for (int k = 0; k < 16; ++k) wn[k] = w_hh[(64 + j) * 32 + ko + k] * (2.0f * L2E);
  float wxr[6], wxz[6], wxn[6];
#pragma unroll
  for (int i = 0; i < 6; ++i) wxr[i] = w_ih[j * 6 + i] * (0.5f * L2E);
#pragma unroll
  for (int i = 0; i < 6; ++i) wxz[i] = w_ih[(32 + j) * 6 + i] * (0.5f * L2E);
#pragma unroll
  for (int i = 0; i < 6; ++i) wxn[i] = w_ih[(64 + j) * 6 + i] * (2.0f * L2E);
  const float br = (b_ih[j] + b_hh[j]) * (0.5f * L2E);
  const float bz = (b_ih[32 + j] + b_hh[32 + j]) * (0.5f * L2E);
  const float bxn = b_ih[64 + j] * (2.0f * L2E);
  const float bhn = b_hh[64 + j] * L2E;
  const float fcw = fc_w[half * 32 + j];
  const float fcb = fc_b[half];

  const float* xb = x + (size_t)b * (TT * 6);
  float* ob = out + (size_t)b * (TT * 2);
  const int bko = half << 6;
  float h = 0.0f;

  v2f cx[3], nx[3];
  {
    const v2f* xp = (const v2f*)xb;
    cx[0] = xp[0]; cx[1] = xp[1]; cx[2] = xp[2];
  }
  for (int t = 0; t < len; ++t) {
    const int tn = (t + 1 < len) ? (t + 1) : t;
    const v2f* xp = (const v2f*)(xb + tn * 6);
    nx[0] = xp[0]; nx[1] = xp[1]; nx[2] = xp[2];
    float xr = br, xz = bz, xn = bxn;
#pragma unroll
    for (int i = 0; i < 3; ++i) {
      const float c0 = cx[i][0], c1 = cx[i][1];
      xr = fmaf(wxr[2 * i], c0, xr); xr = fmaf(wxr[2 * i + 1], c1, xr);
      xz = fmaf(wxz[2 * i], c0, xz); xz = fmaf(wxz[2 * i + 1], c1, xz);
      xn = fmaf(wxn[2 * i], c0, xn); xn = fmaf(wxn[2 * i + 1], c1, xn);
    }
    float hbv[16];
#pragma unroll
    for (int k = 0; k < 16; ++k) hbv[k] = bpermf(bko + (k << 2), h);
    float ar0 = xr, ar1 = 0.f, az0 = xz, az1 = 0.f, an0 = bhn, an1 = 0.f;
#pragma unroll
    for (int k = 0; k < 8; ++k) {
      ar0 = fmaf(wr[k], hbv[k], ar0);
      ar1 = fmaf(wr[k + 8], hbv[k + 8], ar1);
      az0 = fmaf(wz[k], hbv[k], az0);
      az1 = fmaf(wz[k + 8], hbv[k + 8], az1);
      an0 = fmaf(wn[k], hbv[k], an0);
      an1 = fmaf(wn[k + 8], hbv[k + 8], an1);
    }
    const float sr = xhalf_sum(ar0 + ar1);
    const float r = __builtin_amdgcn_rcpf(1.0f + fexp2(-sr));
    const float sz = xhalf_sum(az0 + az1);
    const float z = __builtin_amdgcn_rcpf(1.0f + fexp2(-sz));
    const float hn = xhalf_sum(an0 + an1);
    const float ap = fmaf(r, hn, xn);
    const float qq = __builtin_amdgcn_rcpf(1.0f + fexp2(-ap));
    const float nn = fmaf(2.0f, qq, -1.0f);
    h = fmaf(z, h - nn, nn);
    float p = h * fcw;
    p += __shfl_xor(p, 1);
    p += __shfl_xor(p, 2);
    p += __shfl_xor(p, 4);
    p += __shfl_xor(p, 8);
    p += __shfl_xor(p, 16);
    if (j == 0) ob[t * 2 + half] = p + fcb;
#pragma unroll
    for (int i = 0; i < 3; ++i) cx[i] = nx[i];
  }
  const float fb0 = fc_b[0], fb1 = fc_b[1];
  for (int idx = len * 2 + l; idx < TT * 2; idx += 64)
    ob[idx] = (idx & 1) ? fb1 : fb0;
}

extern "C" void kernel_launch(void* const* d_in, const int* in_sizes, int n_in,
                              void* d_out, int out_size, void* d_ws, size_t ws_size,
                              hipStream_t stream) {
  const float* x       = (const float*)d_in[0];
  const int*   lengths = (const int*)d_in[1];
  const float* w_ih    = (const float*)d_in[2];
  const float* w_hh    = (const float*)d_in[3];
  const float* b_ih    = (const float*)d_in[4];
  const float* b_hh    = (const float*)d_in[5];
  const float* fc_w    = (const float*)d_in[6];
  const float* fc_b    = (const float*)d_in[7];
  float* outp = (float*)d_out;

  const size_t hbuf_elems = (size_t)BB * TT * 32;               // 64 MB
  const size_t gx_elems   = (size_t)BB * TT * 96;               // 192 MB
  const size_t need = (hbuf_elems + gx_elems) * sizeof(float);  // 256 MB
  if (ws_size >= need) {
    float* hbuf = (float*)d_ws;
    float* gx = (float*)d_ws + hbuf_elems;
    hipLaunchKernelGGL(gx_pre, dim3((BB * TT * 96) / 256), dim3(256), 0, stream,
                       x, w_ih, b_ih, b_hh, lengths, gx);
    hipLaunchKernelGGL(gru_seq, dim3(BB), dim3(64), 0, stream,
                       lengths, w_hh, b_hh, gx, hbuf);
    hipLaunchKernelGGL(fc_apply, dim3((BB * TT) / 256), dim3(256), 0, stream,
                       hbuf, lengths, fc_w, fc_b, outp);
  } else {
    hipLaunchKernelGGL(gru_fallback, dim3(BB), dim3(64), 0, stream,
                       x, lengths, w_ih, w_hh, b_ih, b_hh, fc_w, fc_b, outp);
  }
}

// Round 18
// 820.540 us; speedup vs baseline: 1.2575x; 1.0599x over previous
//
#include <hip/hip_runtime.h>

#define TT 4096
#define BB 128
#define L2E 1.4426950408889634f

typedef unsigned uv2 __attribute__((ext_vector_type(2)));
typedef float v2f __attribute__((ext_vector_type(2)));
typedef float v4f __attribute__((ext_vector_type(4)));
typedef __bf16 v8bf __attribute__((ext_vector_type(8)));

__device__ __forceinline__ float fexp2(float a) { return __builtin_amdgcn_exp2f(a); }

__device__ __forceinline__ float bpermf(int idx_bytes, float v) {
  return __int_as_float(__builtin_amdgcn_ds_bpermute(idx_bytes, __float_as_int(v)));
}

// (fallback kernel only)
__device__ __forceinline__ float xhalf_sum(float p) {
#if __has_builtin(__builtin_amdgcn_permlane32_swap)
  uv2 r = __builtin_amdgcn_permlane32_swap(__float_as_uint(p), __float_as_uint(p),
                                           false, false);
  return __uint_as_float(r[0]) + __uint_as_float(r[1]);
#else
  return p + bpermf((threadIdx.x ^ 32) << 2, p);
#endif
}

// pack two f32 -> 2xbf16 dword (RNE)
__device__ __forceinline__ unsigned cvtpk(float lo, float hi) {
  unsigned r;
  asm("v_cvt_pk_bf16_f32 %0, %1, %2" : "=v"(r) : "v"(lo), "v"(hi));
  return r;
}

template <int CTRL>
__device__ __forceinline__ int dppmv(int src) {
  return __builtin_amdgcn_update_dpp(0, src, CTRL, 0xF, 0xF, true);
}

__device__ __forceinline__ v8bf frag_from(unsigned u0, unsigned u1, unsigned u2,
                                          unsigned u3) {
  uint4 uu = make_uint4(u0, u1, u2, u3);
  return __builtin_bit_cast(v8bf, uu);
}

// gx[b,t,g]: g<64  -> L2E*(x.w_ih[g] + b_ih[g] + b_hh[g])   (r,z pre-activation)
//            g>=64 -> 2*L2E*(x.w_ih[g] + b_ih[g])           (n x-side)
__global__ __launch_bounds__(256) void gx_pre(
    const float* __restrict__ x, const float* __restrict__ w_ih,
    const float* __restrict__ b_ih, const float* __restrict__ b_hh,
    const int* __restrict__ lengths, float* __restrict__ gx) {
  const size_t idx = (size_t)blockIdx.x * 256 + threadIdx.x;  // (b*T+t)*96+g
  const int g = (int)(idx % 96);
  const size_t bt = idx / 96;
  const int b = (int)(bt >> 12);
  const int t = (int)(bt & (TT - 1));
  if (t >= lengths[b]) return;
  const float* xp = x + bt * 6;
  float acc = (g < 64) ? (b_ih[g] + b_hh[g]) : b_ih[g];
#pragma unroll
  for (int i = 0; i < 6; ++i) acc = fmaf(w_ih[g * 6 + i], xp[i], acc);
  gx[idx] = (g < 64) ? (L2E * acc) : (2.0f * L2E * acc);
}

// MFMA GRU (R17 structure), gx prefetch deepened 4 -> 8 slots.
// Theory: R14 (bperm gather) == R17 (DPP gather) == 761us implies the gather
// was never critical; the shared ~446cy/step floor matches the gx load
// round-trip (~1800cy) divided by the 4-slot pipeline depth. Depth 8 halves
// that floor; compute chain (~280cy) should become the limiter.
__global__ __launch_bounds__(64) __attribute__((amdgpu_waves_per_eu(1, 1)))
void gru_seq(const int* __restrict__ lengths, const float* __restrict__ w_hh,
             const float* __restrict__ b_hh, const float* __restrict__ gx,
             float* __restrict__ hbuf) {
  __shared__ alignas(16) float hring[2][32][32];  // buf, step, j = 8 KB

  const int b = blockIdx.x;
  const int l = threadIdx.x;
  const int j = l & 31;
  const int len = lengths[b];
  const int n_ = l & 15;                         // B/D column this lane carries
  const int g = l >> 4;                          // 16-lane row index
  const int koff = 16 * (g & 1) + 8 * (g >> 1);  // this row's k-octet base

  // DPP gather selection (row_ror:n => dest[i] = src[(i-n)&15]; s = q_ - qb)
  const int q_ = (l >> 2) & 3;
  const int qb = 2 * (l >> 5);
  const int s0 = (q_ - qb) & 3;
  const int s1 = (q_ - qb - 1) & 3;
  const bool s0a = s0 & 1, s0b = s0 & 2;
  const bool s1a = s1 & 1, s1b = s1 & 2;

  // 6 constant B fragments: B[k=koff+e][n] = W[grow + jb + n][koff+e] * scale
  auto make_wfrag = [&](int grow, int jb, float scale) -> v8bf {
    const float* wrow = w_hh + (grow + jb + n_) * 32 + koff;
    unsigned u0 = cvtpk(wrow[0] * scale, wrow[1] * scale);
    unsigned u1 = cvtpk(wrow[2] * scale, wrow[3] * scale);
    unsigned u2 = cvtpk(wrow[4] * scale, wrow[5] * scale);
    unsigned u3 = cvtpk(wrow[6] * scale, wrow[7] * scale);
    return frag_from(u0, u1, u2, u3);
  };
  const v8bf fR0 = make_wfrag(0, 0, L2E),          fR1 = make_wfrag(0, 16, L2E);
  const v8bf fZ0 = make_wfrag(32, 0, L2E),         fZ1 = make_wfrag(32, 16, L2E);
  const v8bf fN0 = make_wfrag(64, 0, 2.0f * L2E),  fN1 = make_wfrag(64, 16, 2.0f * L2E);
  v4f cn0, cn1;
  {
    const float c0 = 2.0f * L2E * b_hh[64 + n_];
    const float c1 = 2.0f * L2E * b_hh[80 + n_];
    cn0 = v4f{c0, c0, c0, c0};
    cn1 = v4f{c1, c1, c1, c1};
  }
  const v4f zero4 = v4f{0.f, 0.f, 0.f, 0.f};
  const bool hiSel = (g & 1);  // j >= 16 <=> use jb=16 fragment

  const float* gxb = gx + (size_t)b * TT * 96;
  float* hrow = hbuf + (size_t)b * TT * 32;

  float h = 0.0f;
  int t = 0;

  // 8-deep gx prefetch slots (named scalars; static indexing only)
  float g0r, g0z, g0n, g1r, g1z, g1n, g2r, g2z, g2n, g3r, g3z, g3n;
  float g4r, g4z, g4n, g5r, g5z, g5n, g6r, g6z, g6n, g7r, g7z, g7n;
  {
    auto ld = [&](int ti, float& R, float& Z, float& N) {
      const int tc = (ti < len) ? ti : (len - 1);
      const float* p = gxb + (size_t)tc * 96;
      R = p[j]; Z = p[32 + j]; N = p[64 + j];
    };
    ld(0, g0r, g0z, g0n); ld(1, g1r, g1z, g1n);
    ld(2, g2r, g2z, g2n); ld(3, g3r, g3z, g3n);
    ld(4, g4r, g4z, g4n); ld(5, g5r, g5z, g5n);
    ld(6, g6r, g6z, g6n); ld(7, g7r, g7z, g7n);
  }

  auto flush = [&](int base, int cnt) {
    const float4* src = (const float4*)(&hring[(base >> 5) & 1][0][0]);
    float4* dst = (float4*)(hrow + (size_t)base * 32);
    const int n4 = cnt * 8;
    for (int qq = l; qq < n4; qq += 64) dst[qq] = src[qq];
  };

  auto step = [&](float& GR, float& GZ, float& GN) {
    const float xr_ = GR, xz_ = GZ, xn_ = GN;
    // refill this slot for t+8 (8 steps of latency slack)
    {
      const int tp = (t + 8 < len) ? (t + 8) : (len - 1);
      const float* gp = gxb + (size_t)tp * 96;
      GR = gp[j]; GZ = gp[32 + j]; GN = gp[64 + j];
    }

    // ---- A-frag rebuild: pure DPP/VALU, all within this lane's 16-row ----
    const int hi_ = __float_as_int(h);
    const int qa = dppmv<0x00>(hi_), qbv = dppmv<0x55>(hi_);
    const int qc = dppmv<0xAA>(hi_), qd = dppmv<0xFF>(hi_);
    const unsigned u0 = cvtpk(__int_as_float(qa), __int_as_float(qbv));
    const unsigned u1 = cvtpk(__int_as_float(qc), __int_as_float(qd));
    const int r4u0 = dppmv<0x124>((int)u0), r8u0 = dppmv<0x128>((int)u0),
              r12u0 = dppmv<0x12C>((int)u0);
    const int r4u1 = dppmv<0x124>((int)u1), r8u1 = dppmv<0x128>((int)u1),
              r12u1 = dppmv<0x12C>((int)u1);
    const unsigned d0 = s0b ? (s0a ? (unsigned)r12u0 : (unsigned)r8u0)
                            : (s0a ? (unsigned)r4u0 : u0);
    const unsigned d1 = s0b ? (s0a ? (unsigned)r12u1 : (unsigned)r8u1)
                            : (s0a ? (unsigned)r4u1 : u1);
    const unsigned d2 = s1b ? (s1a ? (unsigned)r12u0 : (unsigned)r8u0)
                            : (s1a ? (unsigned)r4u0 : u0);
    const unsigned d3 = s1b ? (s1a ? (unsigned)r12u1 : (unsigned)r8u1)
                            : (s1a ? (unsigned)r4u1 : u1);
    const v8bf ha = frag_from(d0, d1, d2, d3);

    // 6 independent MFMAs: full K=32 dot per gate-half
    const v4f yr0 = __builtin_amdgcn_mfma_f32_16x16x32_bf16(ha, fR0, zero4, 0, 0, 0);
    const v4f yr1 = __builtin_amdgcn_mfma_f32_16x16x32_bf16(ha, fR1, zero4, 0, 0, 0);
    const v4f yz0 = __builtin_amdgcn_mfma_f32_16x16x32_bf16(ha, fZ0, zero4, 0, 0, 0);
    const v4f yz1 = __builtin_amdgcn_mfma_f32_16x16x32_bf16(ha, fZ1, zero4, 0, 0, 0);
    const v4f yn0 = __builtin_amdgcn_mfma_f32_16x16x32_bf16(ha, fN0, cn0, 0, 0, 0);
    const v4f yn1 = __builtin_amdgcn_mfma_f32_16x16x32_bf16(ha, fN1, cn1, 0, 0, 0);

    const float yr = hiSel ? yr1[0] : yr0[0];
    const float yz = hiSel ? yz1[0] : yz0[0];
    const float hn = hiSel ? yn1[0] : yn0[0];  // incl. bhn via C

    const float r_ = __builtin_amdgcn_rcpf(1.0f + fexp2(-(yr + xr_)));
    const float z_ = __builtin_amdgcn_rcpf(1.0f + fexp2(-(yz + xz_)));
    const float ap = fmaf(r_, hn, xn_);
    const float q0 = __builtin_amdgcn_rcpf(1.0f + fexp2(-ap));
    const float nn = fmaf(2.0f, q0, -1.0f);
    h = fmaf(z_, h - nn, nn);

    hring[(t >> 5) & 1][t & 31][j] = h;  // duplicate halves write same value
    if ((t & 31) == 31) flush(t - 31, 32);
    ++t;
  };

  while (t + 8 <= len) {
    step(g0r, g0z, g0n);
    step(g1r, g1z, g1n);
    step(g2r, g2z, g2n);
    step(g3r, g3z, g3n);
    step(g4r, g4z, g4n);
    step(g5r, g5z, g5n);
    step(g6r, g6z, g6n);
    step(g7r, g7z, g7n);
  }
  if (t < len) step(g0r, g0z, g0n);
  if (t < len) step(g1r, g1z, g1n);
  if (t < len) step(g2r, g2z, g2n);
  if (t < len) step(g3r, g3z, g3n);
  if (t < len) step(g4r, g4z, g4n);
  if (t < len) step(g5r, g5z, g5n);
  if (t < len) step(g6r, g6z, g6n);

  const int rem = len & 31;
  if (rem) flush(len - rem, rem);
}

// out[b,t,:] = (t < len[b]) ? h[b,t,:] @ fc_w^T + fc_b : fc_b
__global__ __launch_bounds__(256) void fc_apply(
    const float* __restrict__ hbuf, const int* __restrict__ lengths,
    const float* __restrict__ fc_w, const float* __restrict__ fc_b,
    float* __restrict__ out) {
  const int idx = blockIdx.x * 256 + threadIdx.x;  // flattened (b,t)
  const int b = idx >> 12;
  const int t = idx & (TT - 1);
  const float fb0 = fc_b[0], fb1 = fc_b[1];
  float* op = out + (size_t)idx * 2;
  if (t >= lengths[b]) {
    op[0] = fb0;
    op[1] = fb1;
    return;
  }
  const float4* hp = (const float4*)(hbuf + (size_t)idx * 32);
  const float4* w0 = (const float4*)(fc_w);
  const float4* w1 = (const float4*)(fc_w + 32);
  float o0 = 0.f, o1 = 0.f;
#pragma unroll
  for (int qq = 0; qq < 8; ++qq) {
    const float4 hv = hp[qq], a = w0[qq], c = w1[qq];
    o0 += hv.x * a.x + hv.y * a.y + hv.z * a.z + hv.w * a.w;
    o1 += hv.x * c.x + hv.y * c.y + hv.z * c.z + hv.w * c.w;
  }
  op[0] = o0 + fb0;
  op[1] = o1 + fb1;
}

// Fallback (ws too small): self-contained single kernel (R6 structure).
__global__ __launch_bounds__(64) void gru_fallback(
    const float* __restrict__ x, const int* __restrict__ lengths,
    const float* __restrict__ w_ih, const float* __restrict__ w_hh,
    const float* __restrict__ b_ih, const float* __restrict__ b_hh,
    const float* __restrict__ fc_w, const float* __restrict__ fc_b,
    float* __restrict__ out) {
  const int b = blockIdx.x;
  const int l = threadIdx.x;
  const int j = l & 31;
  const int half = l >> 5;
  const int ko = half << 4;
  const int len = lengths[b];

  float wr[16], wz[16], wn[16];
#pragma unroll
  for (int k = 0; k < 16; ++k) wr[k] = w_hh[j * 32 + ko + k] * L2E;
#pragma unroll
  for (int k = 0; k < 16; ++k) wz[k] = w_hh[(32 + j) * 32 + ko + k] * L2E;
#pragma unroll
  for (int k = 0; k < 16; ++k) wn[k] = w_hh[(64 + j) * 32 + ko + k] * (2.0f * L2E);
  float wxr[6], wxz[6], wxn[6];
#pragma unroll
  for (int i = 0; i < 6; ++i) wxr[i] = w_ih[j * 6 + i] * (0.5f * L2E);
#pragma unroll
  for (int i = 0; i < 6; ++i) wxz[i] = w_ih[(32 + j) * 6 + i] * (0.5f * L2E);
#pragma unroll
  for (int i = 0; i < 6; ++i) wxn[i] = w_ih[(64 + j) * 6 + i] * (2.0f * L2E);
  const float br = (b_ih[j] + b_hh[j]) * (0.5f * L2E);
  const float bz = (b_ih[32 + j] + b_hh[32 + j]) * (0.5f * L2E);
  const float bxn = b_ih[64 + j] * (2.0f * L2E);
  const float bhn = b_hh[64 + j] * L2E;
  const float fcw = fc_w[half * 32 + j];
  const float fcb = fc_b[half];

  const float* xb = x + (size_t)b * (TT * 6);
  float* ob = out + (size_t)b * (TT * 2);
  const int bko = half << 6;
  float h = 0.0f;

  v2f cx[3], nx[3];
  {
    const v2f* xp = (const v2f*)xb;
    cx[0] = xp[0]; cx[1] = xp[1]; cx[2] = xp[2];
  }
  for (int t = 0; t < len; ++t) {
    const int tn = (t + 1 < len) ? (t + 1) : t;
    const v2f* xp = (const v2f*)(xb + tn * 6);
    nx[0] = xp[0]; nx[1] = xp[1]; nx[2] = xp[2];
    float xr = br, xz = bz, xn = bxn;
#pragma unroll
    for (int i = 0; i < 3; ++i) {
      const float c0 = cx[i][0], c1 = cx[i][1];
      xr = fmaf(wxr[2 * i], c0, xr); xr = fmaf(wxr[2 * i + 1], c1, xr);
      xz = fmaf(wxz[2 * i], c0, xz); xz = fmaf(wxz[2 * i + 1], c1, xz);
      xn = fmaf(wxn[2 * i], c0, xn); xn = fmaf(wxn[2 * i + 1], c1, xn);
    }
    float hbv[16];
#pragma unroll
    for (int k = 0; k < 16; ++k) hbv[k] = bpermf(bko + (k << 2), h);
    float ar0 = xr, ar1 = 0.f, az0 = xz, az1 = 0.f, an0 = bhn, an1 = 0.f;
#pragma unroll
    for (int k = 0; k < 8; ++k) {
      ar0 = fmaf(wr[k], hbv[k], ar0);
      ar1 = fmaf(wr[k + 8], hbv[k + 8], ar1);
      az0 = fmaf(wz[k], hbv[k], az0);
      az1 = fmaf(wz[k + 8], hbv[k + 8], az1);
      an0 = fmaf(wn[k], hbv[k], an0);
      an1 = fmaf(wn[k + 8], hbv[k + 8], an1);
    }
    const float sr = xhalf_sum(ar0 + ar1);
    const float r = __builtin_amdgcn_rcpf(1.0f + fexp2(-sr));
    const float sz = xhalf_sum(az0 + az1);
    const float z = __builtin_amdgcn_rcpf(1.0f + fexp2(-sz));
    const float hn = xhalf_sum(an0 + an1);
    const float ap = fmaf(r, hn, xn);
    const float qq = __builtin_amdgcn_rcpf(1.0f + fexp2(-ap));
    const float nn = fmaf(2.0f, qq, -1.0f);
    h = fmaf(z, h - nn, nn);
    float p = h * fcw;
    p += __shfl_xor(p, 1);
    p += __shfl_xor(p, 2);
    p += __shfl_xor(p, 4);
    p += __shfl_xor(p, 8);
    p += __shfl_xor(p, 16);
    if (j == 0) ob[t * 2 + half] = p + fcb;
#pragma unroll
    for (int i = 0; i < 3; ++i) cx[i] = nx[i];
  }
  const float fb0 = fc_b[0], fb1 = fc_b[1];
  for (int idx = len * 2 + l; idx < TT * 2; idx += 64)
    ob[idx] = (idx & 1) ? fb1 : fb0;
}

extern "C" void kernel_launch(void* const* d_in, const int* in_sizes, int n_in,
                              void* d_out, int out_size, void* d_ws, size_t ws_size,
                              hipStream_t stream) {
  const float* x       = (const float*)d_in[0];
  const int*   lengths = (const int*)d_in[1];
  const float* w_ih    = (const float*)d_in[2];
  const float* w_hh    = (const float*)d_in[3];
  const float* b_ih    = (const float*)d_in[4];
  const float* b_hh    = (const float*)d_in[5];
  const float* fc_w    = (const float*)d_in[6];
  const float* fc_b    = (const float*)d_in[7];
  float* outp = (float*)d_out;

  const size_t hbuf_elems = (size_t)BB * TT * 32;               // 64 MB
  const size_t gx_elems   = (size_t)BB * TT * 96;               // 192 MB
  const size_t need = (hbuf_elems + gx_elems) * sizeof(float);  // 256 MB
  if (ws_size >= need) {
    float* hbuf = (float*)d_ws;
    float* gx = (float*)d_ws + hbuf_elems;
    hipLaunchKernelGGL(gx_pre, dim3((BB * TT * 96) / 256), dim3(256), 0, stream,
                       x, w_ih, b_ih, b_hh, lengths, gx);
    hipLaunchKernelGGL(gru_seq, dim3(BB), dim3(64), 0, stream,
                       lengths, w_hh, b_hh, gx, hbuf);
    hipLaunchKernelGGL(fc_apply, dim3((BB * TT) / 256), dim3(256), 0, stream,
                       hbuf, lengths, fc_w, fc_b, outp);
  } else {
    hipLaunchKernelGGL(gru_fallback, dim3(BB), dim3(64), 0, stream,
                       x, lengths, w_ih, w_hh, b_ih, b_hh, fc_w, fc_b, outp);
  }
}

// Round 19
// 807.965 us; speedup vs baseline: 1.2771x; 1.0156x over previous
//
#include <hip/hip_runtime.h>

#define TT 4096
#define BB 128
#define L2E 1.4426950408889634f

typedef unsigned uv2 __attribute__((ext_vector_type(2)));
typedef float v2f __attribute__((ext_vector_type(2)));
typedef float v4f __attribute__((ext_vector_type(4)));
typedef __bf16 v8bf __attribute__((ext_vector_type(8)));

__device__ __forceinline__ float fexp2(float a) { return __builtin_amdgcn_exp2f(a); }

__device__ __forceinline__ float bpermf(int idx_bytes, float v) {
  return __int_as_float(__builtin_amdgcn_ds_bpermute(idx_bytes, __float_as_int(v)));
}

// (fallback kernel only)
__device__ __forceinline__ float xhalf_sum(float p) {
#if __has_builtin(__builtin_amdgcn_permlane32_swap)
  uv2 r = __builtin_amdgcn_permlane32_swap(__float_as_uint(p), __float_as_uint(p),
                                           false, false);
  return __uint_as_float(r[0]) + __uint_as_float(r[1]);
#else
  return p + bpermf((threadIdx.x ^ 32) << 2, p);
#endif
}

// pack two f32 -> 2xbf16 dword (RNE)
__device__ __forceinline__ unsigned cvtpk(float lo, float hi) {
  unsigned r;
  asm("v_cvt_pk_bf16_f32 %0, %1, %2" : "=v"(r) : "v"(lo), "v"(hi));
  return r;
}

template <int CTRL>
__device__ __forceinline__ int dppmv(int src) {
  return __builtin_amdgcn_update_dpp(0, src, CTRL, 0xF, 0xF, true);
}

__device__ __forceinline__ v8bf frag_from(unsigned u0, unsigned u1, unsigned u2,
                                          unsigned u3) {
  uint4 uu = make_uint4(u0, u1, u2, u3);
  return __builtin_bit_cast(v8bf, uu);
}

// gx[b,t,g]: g<64  -> L2E*(x.w_ih[g] + b_ih[g] + b_hh[g])   (r,z pre-activation)
//            g>=64 -> 2*L2E*(x.w_ih[g] + b_ih[g])           (n x-side)
__global__ __launch_bounds__(256) void gx_pre(
    const float* __restrict__ x, const float* __restrict__ w_ih,
    const float* __restrict__ b_ih, const float* __restrict__ b_hh,
    const int* __restrict__ lengths, float* __restrict__ gx) {
  const size_t idx = (size_t)blockIdx.x * 256 + threadIdx.x;  // (b*T+t)*96+g
  const int g = (int)(idx % 96);
  const size_t bt = idx / 96;
  const int b = (int)(bt >> 12);
  const int t = (int)(bt & (TT - 1));
  if (t >= lengths[b]) return;
  const float* xp = x + bt * 6;
  float acc = (g < 64) ? (b_ih[g] + b_hh[g]) : b_ih[g];
#pragma unroll
  for (int i = 0; i < 6; ++i) acc = fmaf(w_ih[g * 6 + i], xp[i], acc);
  gx[idx] = (g < 64) ? (L2E * acc) : (2.0f * L2E * acc);
}

// MFMA GRU (R18 structure) with the FC epilogue FUSED into the 32-step flush:
// lanes 0-31 compute out[base+i][0], lanes 32-63 out[base+i][1] directly from
// the LDS hring (dot with the preloaded fc_w row) — fc_apply kernel and the
// 64MB hbuf round-trip are gone. The t>=len constant fill runs in the block
// epilogue. Serial spine per step (~420cy: DPP gather ~30, MFMA dep ~80,
// 4-deep trans tail ~200) is unchanged — fc work issues in its stall slots.
__global__ __launch_bounds__(64) __attribute__((amdgpu_waves_per_eu(1, 1)))
void gru_seq(const int* __restrict__ lengths, const float* __restrict__ w_hh,
             const float* __restrict__ b_hh, const float* __restrict__ gx,
             const float* __restrict__ fc_w, const float* __restrict__ fc_b,
             float* __restrict__ out) {
  __shared__ alignas(16) float hring[2][32][32];  // buf, step, j = 8 KB

  const int b = blockIdx.x;
  const int l = threadIdx.x;
  const int j = l & 31;
  const int len = lengths[b];
  const int n_ = l & 15;                         // B/D column this lane carries
  const int g = l >> 4;                          // 16-lane row index
  const int koff = 16 * (g & 1) + 8 * (g >> 1);  // this row's k-octet base

  // DPP gather selection (row_ror:n => dest[i] = src[(i-n)&15]; s = q_ - qb)
  const int q_ = (l >> 2) & 3;
  const int qb = 2 * (l >> 5);
  const int s0 = (q_ - qb) & 3;
  const int s1 = (q_ - qb - 1) & 3;
  const bool s0a = s0 & 1, s0b = s0 & 2;
  const bool s1a = s1 & 1, s1b = s1 & 2;

  // 6 constant B fragments: B[k=koff+e][n] = W[grow + jb + n][koff+e] * scale
  auto make_wfrag = [&](int grow, int jb, float scale) -> v8bf {
    const float* wrow = w_hh + (grow + jb + n_) * 32 + koff;
    unsigned u0 = cvtpk(wrow[0] * scale, wrow[1] * scale);
    unsigned u1 = cvtpk(wrow[2] * scale, wrow[3] * scale);
    unsigned u2 = cvtpk(wrow[4] * scale, wrow[5] * scale);
    unsigned u3 = cvtpk(wrow[6] * scale, wrow[7] * scale);
    return frag_from(u0, u1, u2, u3);
  };
  const v8bf fR0 = make_wfrag(0, 0, L2E),          fR1 = make_wfrag(0, 16, L2E);
  const v8bf fZ0 = make_wfrag(32, 0, L2E),         fZ1 = make_wfrag(32, 16, L2E);
  const v8bf fN0 = make_wfrag(64, 0, 2.0f * L2E),  fN1 = make_wfrag(64, 16, 2.0f * L2E);
  v4f cn0, cn1;
  {
    const float c0 = 2.0f * L2E * b_hh[64 + n_];
    const float c1 = 2.0f * L2E * b_hh[80 + n_];
    cn0 = v4f{c0, c0, c0, c0};
    cn1 = v4f{c1, c1, c1, c1};
  }
  const v4f zero4 = v4f{0.f, 0.f, 0.f, 0.f};
  const bool hiSel = (g & 1);  // j >= 16 <=> use jb=16 fragment

  // FC: lane o = l>>5 handles output column o; preload its fc_w row (8 float4)
  const int o_ = l >> 5;
  float4 fcw4[8];
  {
    const float4* wp = (const float4*)(fc_w + o_ * 32);
#pragma unroll
    for (int qq = 0; qq < 8; ++qq) fcw4[qq] = wp[qq];
  }
  const float fcb_ = fc_b[o_];
  const float fb0 = fc_b[0], fb1 = fc_b[1];

  const float* gxb = gx + (size_t)b * TT * 96;
  float* ob = out + (size_t)b * TT * 2;

  float h = 0.0f;
  int t = 0;

  // 8-deep gx prefetch slots (named scalars; static indexing only)
  float g0r, g0z, g0n, g1r, g1z, g1n, g2r, g2z, g2n, g3r, g3z, g3n;
  float g4r, g4z, g4n, g5r, g5z, g5n, g6r, g6z, g6n, g7r, g7z, g7n;
  {
    auto ld = [&](int ti, float& R, float& Z, float& N) {
      const int tc = (ti < len) ? ti : (len - 1);
      const float* p = gxb + (size_t)tc * 96;
      R = p[j]; Z = p[32 + j]; N = p[64 + j];
    };
    ld(0, g0r, g0z, g0n); ld(1, g1r, g1z, g1n);
    ld(2, g2r, g2z, g2n); ld(3, g3r, g3z, g3n);
    ld(4, g4r, g4z, g4n); ld(5, g5r, g5z, g5n);
    ld(6, g6r, g6z, g6n); ld(7, g7r, g7z, g7n);
  }

  // flush with fused FC: steps [base, base+cnt) -> out[base+i][o_]
  auto flush = [&](int base, int cnt) {
    const int i = l & 31;
    if (i < cnt) {
      const float4* hp = (const float4*)(&hring[(base >> 5) & 1][i][0]);
      float acc = 0.f;
#pragma unroll
      for (int qq = 0; qq < 8; ++qq) {
        const float4 hv = hp[qq], w = fcw4[qq];
        acc += hv.x * w.x + hv.y * w.y + hv.z * w.z + hv.w * w.w;
      }
      ob[(base + i) * 2 + o_] = acc + fcb_;
    }
  };

  auto step = [&](float& GR, float& GZ, float& GN) {
    const float xr_ = GR, xz_ = GZ, xn_ = GN;
    // refill this slot for t+8 (8 steps of latency slack)
    {
      const int tp = (t + 8 < len) ? (t + 8) : (len - 1);
      const float* gp = gxb + (size_t)tp * 96;
      GR = gp[j]; GZ = gp[32 + j]; GN = gp[64 + j];
    }

    // ---- A-frag rebuild: pure DPP/VALU, all within this lane's 16-row ----
    const int hi_ = __float_as_int(h);
    const int qa = dppmv<0x00>(hi_), qbv = dppmv<0x55>(hi_);
    const int qc = dppmv<0xAA>(hi_), qd = dppmv<0xFF>(hi_);
    const unsigned u0 = cvtpk(__int_as_float(qa), __int_as_float(qbv));
    const unsigned u1 = cvtpk(__int_as_float(qc), __int_as_float(qd));
    const int r4u0 = dppmv<0x124>((int)u0), r8u0 = dppmv<0x128>((int)u0),
              r12u0 = dppmv<0x12C>((int)u0);
    const int r4u1 = dppmv<0x124>((int)u1), r8u1 = dppmv<0x128>((int)u1),
              r12u1 = dppmv<0x12C>((int)u1);
    const unsigned d0 = s0b ? (s0a ? (unsigned)r12u0 : (unsigned)r8u0)
                            : (s0a ? (unsigned)r4u0 : u0);
    const unsigned d1 = s0b ? (s0a ? (unsigned)r12u1 : (unsigned)r8u1)
                            : (s0a ? (unsigned)r4u1 : u1);
    const unsigned d2 = s1b ? (s1a ? (unsigned)r12u0 : (unsigned)r8u0)
                            : (s1a ? (unsigned)r4u0 : u0);
    const unsigned d3 = s1b ? (s1a ? (unsigned)r12u1 : (unsigned)r8u1)
                            : (s1a ? (unsigned)r4u1 : u1);
    const v8bf ha = frag_from(d0, d1, d2, d3);

    // 6 independent MFMAs: full K=32 dot per gate-half
    const v4f yr0 = __builtin_amdgcn_mfma_f32_16x16x32_bf16(ha, fR0, zero4, 0, 0, 0);
    const v4f yr1 = __builtin_amdgcn_mfma_f32_16x16x32_bf16(ha, fR1, zero4, 0, 0, 0);
    const v4f yz0 = __builtin_amdgcn_mfma_f32_16x16x32_bf16(ha, fZ0, zero4, 0, 0, 0);
    const v4f yz1 = __builtin_amdgcn_mfma_f32_16x16x32_bf16(ha, fZ1, zero4, 0, 0, 0);
    const v4f yn0 = __builtin_amdgcn_mfma_f32_16x16x32_bf16(ha, fN0, cn0, 0, 0, 0);
    const v4f yn1 = __builtin_amdgcn_mfma_f32_16x16x32_bf16(ha, fN1, cn1, 0, 0, 0);

    const float yr = hiSel ? yr1[0] : yr0[0];
    const float yz = hiSel ? yz1[0] : yz0[0];
    const float hn = hiSel ? yn1[0] : yn0[0];  // incl. bhn via C

    const float r_ = __builtin_amdgcn_rcpf(1.0f + fexp2(-(yr + xr_)));
    const float z_ = __builtin_amdgcn_rcpf(1.0f + fexp2(-(yz + xz_)));
    const float ap = fmaf(r_, hn, xn_);
    const float q0 = __builtin_amdgcn_rcpf(1.0f + fexp2(-ap));
    const float nn = fmaf(2.0f, q0, -1.0f);
    h = fmaf(z_, h - nn, nn);

    hring[(t >> 5) & 1][t & 31][j] = h;  // duplicate halves write same value
    if ((t & 31) == 31) flush(t - 31, 32);
    ++t;
  };

  while (t + 8 <= len) {
    step(g0r, g0z, g0n);
    step(g1r, g1z, g1n);
    step(g2r, g2z, g2n);
    step(g3r, g3z, g3n);
    step(g4r, g4z, g4n);
    step(g5r, g5z, g5n);
    step(g6r, g6z, g6n);
    step(g7r, g7z, g7n);
  }
  if (t < len) step(g0r, g0z, g0n);
  if (t < len) step(g1r, g1z, g1n);
  if (t < len) step(g2r, g2z, g2n);
  if (t < len) step(g3r, g3z, g3n);
  if (t < len) step(g4r, g4z, g4n);
  if (t < len) step(g5r, g5z, g5n);
  if (t < len) step(g6r, g6z, g6n);

  const int rem = len & 31;
  if (rem) flush(len - rem, rem);

  // t >= len: ys == 0 -> output is fc_b
  for (int idx2 = len * 2 + l; idx2 < TT * 2; idx2 += 64)
    ob[idx2] = (idx2 & 1) ? fb1 : fb0;
}

// Fallback (ws too small): self-contained single kernel (R6 structure).
__global__ __launch_bounds__(64) void gru_fallback(
    const float* __restrict__ x, const int* __restrict__ lengths,
    const float* __restrict__ w_ih, const float* __restrict__ w_hh,
    const float* __restrict__ b_ih, const float* __restrict__ b_hh,
    const float* __restrict__ fc_w, const float* __restrict__ fc_b,
    float* __restrict__ out) {
  const int b = blockIdx.x;
  const int l = threadIdx.x;
  const int j = l & 31;
  const int half = l >> 5;
  const int ko = half << 4;
  const int len = lengths[b];

  float wr[16], wz[16], wn[16];
#pragma unroll
  for (int k = 0; k < 16; ++k) wr[k] = w_hh[j * 32 + ko + k] * L2E;
#pragma unroll
  for (int k = 0; k < 16; ++k) wz[k] = w_hh[(32 + j) * 32 + ko + k] * L2E;
#pragma unroll
  for (int k = 0; k < 16; ++k) wn[k] = w_hh[(64 + j) * 32 + ko + k] * (2.0f * L2E);
  float wxr[6], wxz[6], wxn[6];
#pragma unroll
  for (int i = 0; i < 6; ++i) wxr[i] = w_ih[j * 6 + i] * (0.5f * L2E);
#pragma unroll
  for (int i = 0; i < 6; ++i) wxz[i] = w_ih[(32 + j) * 6 + i] * (0.5f * L2E);
#pragma unroll
  for (int i = 0; i < 6; ++i) wxn[i] = w_ih[(64 + j) * 6 + i] * (2.0f * L2E);
  const float br = (b_ih[j] + b_hh[j]) * (0.5f * L2E);
  const float bz = (b_ih[32 + j] + b_hh[32 + j]) * (0.5f * L2E);
  const float bxn = b_ih[64 + j] * (2.0f * L2E);
  const float bhn = b_hh[64 + j] * L2E;
  const float fcw = fc_w[half * 32 + j];
  const float fcb = fc_b[half];

  const float* xb = x + (size_t)b * (TT * 6);
  float* ob = out + (size_t)b * (TT * 2);
  const int bko = half << 6;
  float h = 0.0f;

  v2f cx[3], nx[3];
  {
    const v2f* xp = (const v2f*)xb;
    cx[0] = xp[0]; cx[1] = xp[1]; cx[2] = xp[2];
  }
  for (int t = 0; t < len; ++t) {
    const int tn = (t + 1 < len) ? (t + 1) : t;
    const v2f* xp = (const v2f*)(xb + tn * 6);
    nx[0] = xp[0]; nx[1] = xp[1]; nx[2] = xp[2];
    float xr = br, xz = bz, xn = bxn;
#pragma unroll
    for (int i = 0; i < 3; ++i) {
      const float c0 = cx[i][0], c1 = cx[i][1];
      xr = fmaf(wxr[2 * i], c0, xr); xr = fmaf(wxr[2 * i + 1], c1, xr);
      xz = fmaf(wxz[2 * i], c0, xz); xz = fmaf(wxz[2 * i + 1], c1, xz);
      xn = fmaf(wxn[2 * i], c0, xn); xn = fmaf(wxn[2 * i + 1], c1, xn);
    }
    float hbv[16];
#pragma unroll
    for (int k = 0; k < 16; ++k) hbv[k] = bpermf(bko + (k << 2), h);
    float ar0 = xr, ar1 = 0.f, az0 = xz, az1 = 0.f, an0 = bhn, an1 = 0.f;
#pragma unroll
    for (int k = 0; k < 8; ++k) {
      ar0 = fmaf(wr[k], hbv[k], ar0);
      ar1 = fmaf(wr[k + 8], hbv[k + 8], ar1);
      az0 = fmaf(wz[k], hbv[k], az0);
      az1 = fmaf(wz[k + 8], hbv[k + 8], az1);
      an0 = fmaf(wn[k], hbv[k], an0);
      an1 = fmaf(wn[k + 8], hbv[k + 8], an1);
    }
    const float sr = xhalf_sum(ar0 + ar1);
    const float r = __builtin_amdgcn_rcpf(1.0f + fexp2(-sr));
    const float sz = xhalf_sum(az0 + az1);
    const float z = __builtin_amdgcn_rcpf(1.0f + fexp2(-sz));
    const float hn = xhalf_sum(an0 + an1);
    const float ap = fmaf(r, hn, xn);
    const float qq = __builtin_amdgcn_rcpf(1.0f + fexp2(-ap));
    const float nn = fmaf(2.0f, qq, -1.0f);
    h = fmaf(z, h - nn, nn);
    float p = h * fcw;
    p += __shfl_xor(p, 1);
    p += __shfl_xor(p, 2);
    p += __shfl_xor(p, 4);
    p += __shfl_xor(p, 8);
    p += __shfl_xor(p, 16);
    if (j == 0) ob[t * 2 + half] = p + fcb;
#pragma unroll
    for (int i = 0; i < 3; ++i) cx[i] = nx[i];
  }
  const float fb0 = fc_b[0], fb1 = fc_b[1];
  for (int idx = len * 2 + l; idx < TT * 2; idx += 64)
    ob[idx] = (idx & 1) ? fb1 : fb0;
}

extern "C" void kernel_launch(void* const* d_in, const int* in_sizes, int n_in,
                              void* d_out, int out_size, void* d_ws, size_t ws_size,
                              hipStream_t stream) {
  const float* x       = (const float*)d_in[0];
  const int*   lengths = (const int*)d_in[1];
  const float* w_ih    = (const float*)d_in[2];
  const float* w_hh    = (const float*)d_in[3];
  const float* b_ih    = (const float*)d_in[4];
  const float* b_hh    = (const float*)d_in[5];
  const float* fc_w    = (const float*)d_in[6];
  const float* fc_b    = (const float*)d_in[7];
  float* outp = (float*)d_out;

  const size_t gx_elems = (size_t)BB * TT * 96;        // 192 MB
  const size_t need = gx_elems * sizeof(float);
  if (ws_size >= need) {
    float* gx = (float*)d_ws;
    hipLaunchKernelGGL(gx_pre, dim3((BB * TT * 96) / 256), dim3(256), 0, stream,
                       x, w_ih, b_ih, b_hh, lengths, gx);
    hipLaunchKernelGGL(gru_seq, dim3(BB), dim3(64), 0, stream,
                       lengths, w_hh, b_hh, gx, fc_w, fc_b, outp);
  } else {
    hipLaunchKernelGGL(gru_fallback, dim3(BB), dim3(64), 0, stream,
                       x, lengths, w_ih, w_hh, b_ih, b_hh, fc_w, fc_b, outp);
  }
}

// Round 20
// 708.410 us; speedup vs baseline: 1.4565x; 1.1405x over previous
//
#include <hip/hip_runtime.h>

#define TT 4096
#define BB 128
#define L2E 1.4426950408889634f

typedef float v2f __attribute__((ext_vector_type(2)));
typedef float v4f __attribute__((ext_vector_type(4)));
typedef __bf16 v8bf __attribute__((ext_vector_type(8)));

__device__ __forceinline__ float fexp2(float a) { return __builtin_amdgcn_exp2f(a); }

// pack two f32 -> 2xbf16 dword (RNE)
__device__ __forceinline__ unsigned cvtpk(float lo, float hi) {
  unsigned r;
  asm("v_cvt_pk_bf16_f32 %0, %1, %2" : "=v"(r) : "v"(lo), "v"(hi));
  return r;
}

template <int CTRL>
__device__ __forceinline__ int dppmv(int src) {
  return __builtin_amdgcn_update_dpp(0, src, CTRL, 0xF, 0xF, true);
}

__device__ __forceinline__ v8bf frag_from(unsigned u0, unsigned u1, unsigned u2,
                                          unsigned u3) {
  uint4 uu = make_uint4(u0, u1, u2, u3);
  return __builtin_bit_cast(v8bf, uu);
}

// Single fused kernel: GRU recurrence on the MATRIX pipe + inline x-side
// einsum + fused FC epilogue. One wave per batch element.
//
// - W.h matvec: D = A.B, A = h frag (rebuilt per step via quad_perm/cvt_pk/
//   row_ror DPP, pure VALU), B = 6 constant bf16 W fragments. k-map:
//   group g covers k-octet koff(g)=16(g&1)+8(g>>1) so each 16-lane row holds
//   exactly the h-octet it needs (R17, verified). D col = lane&15 (m89).
// - x-side: 18 FMAs/lane from preloaded, prescaled w_ih row j (off-spine;
//   x[t] prefetched 8 slots deep as 3 v2f broadcast loads).
// - FC epilogue fused into the 32-step LDS-ring flush (R19, verified).
// - waves_per_eu(1,1): 512-VGPR budget keeps all weights resident (R9).
__global__ __launch_bounds__(64) __attribute__((amdgpu_waves_per_eu(1, 1)))
void gru_fused(const float* __restrict__ x, const int* __restrict__ lengths,
               const float* __restrict__ w_ih, const float* __restrict__ w_hh,
               const float* __restrict__ b_ih, const float* __restrict__ b_hh,
               const float* __restrict__ fc_w, const float* __restrict__ fc_b,
               float* __restrict__ out) {
  __shared__ alignas(16) float hring[2][32][32];  // buf, step, j = 8 KB

  const int b = blockIdx.x;
  const int l = threadIdx.x;
  const int j = l & 31;
  const int len = lengths[b];
  const int n_ = l & 15;                         // B/D column this lane carries
  const int g = l >> 4;                          // 16-lane row index
  const int koff = 16 * (g & 1) + 8 * (g >> 1);  // this row's k-octet base

  // DPP gather selection (row_ror:n => dest[i] = src[(i-n)&15]; s = q_ - qb)
  const int q_ = (l >> 2) & 3;
  const int qb = 2 * (l >> 5);
  const int s0 = (q_ - qb) & 3;
  const int s1 = (q_ - qb - 1) & 3;
  const bool s0a = s0 & 1, s0b = s0 & 2;
  const bool s1a = s1 & 1, s1b = s1 & 2;

  // 6 constant B fragments: B[k=koff+e][n] = W[grow + jb + n][koff+e] * scale
  auto make_wfrag = [&](int grow, int jb, float scale) -> v8bf {
    const float* wrow = w_hh + (grow + jb + n_) * 32 + koff;
    unsigned u0 = cvtpk(wrow[0] * scale, wrow[1] * scale);
    unsigned u1 = cvtpk(wrow[2] * scale, wrow[3] * scale);
    unsigned u2 = cvtpk(wrow[4] * scale, wrow[5] * scale);
    unsigned u3 = cvtpk(wrow[6] * scale, wrow[7] * scale);
    return frag_from(u0, u1, u2, u3);
  };
  const v8bf fR0 = make_wfrag(0, 0, L2E),          fR1 = make_wfrag(0, 16, L2E);
  const v8bf fZ0 = make_wfrag(32, 0, L2E),         fZ1 = make_wfrag(32, 16, L2E);
  const v8bf fN0 = make_wfrag(64, 0, 2.0f * L2E),  fN1 = make_wfrag(64, 16, 2.0f * L2E);
  v4f cn0, cn1;
  {
    const float c0 = 2.0f * L2E * b_hh[64 + n_];
    const float c1 = 2.0f * L2E * b_hh[80 + n_];
    cn0 = v4f{c0, c0, c0, c0};
    cn1 = v4f{c1, c1, c1, c1};
  }
  const v4f zero4 = v4f{0.f, 0.f, 0.f, 0.f};
  const bool hiSel = (g & 1);  // j >= 16 <=> use jb=16 fragment

  // x-side weights for gate rows j / 32+j / 64+j, pre-scaled (R6 pattern)
  float wxr[6], wxz[6], wxn[6];
#pragma unroll
  for (int i = 0; i < 6; ++i) wxr[i] = w_ih[j * 6 + i] * L2E;
#pragma unroll
  for (int i = 0; i < 6; ++i) wxz[i] = w_ih[(32 + j) * 6 + i] * L2E;
#pragma unroll
  for (int i = 0; i < 6; ++i) wxn[i] = w_ih[(64 + j) * 6 + i] * (2.0f * L2E);
  const float br  = (b_ih[j] + b_hh[j]) * L2E;
  const float bz  = (b_ih[32 + j] + b_hh[32 + j]) * L2E;
  const float bxn = b_ih[64 + j] * (2.0f * L2E);

  // FC: lane o = l>>5 handles output column o; preload its fc_w row (8 float4)
  const int o_ = l >> 5;
  float4 fcw4[8];
  {
    const float4* wp = (const float4*)(fc_w + o_ * 32);
#pragma unroll
    for (int qq = 0; qq < 8; ++qq) fcw4[qq] = wp[qq];
  }
  const float fcb_ = fc_b[o_];
  const float fb0 = fc_b[0], fb1 = fc_b[1];

  const float* xb = x + (size_t)b * TT * 6;
  float* ob = out + (size_t)b * TT * 2;

  float h = 0.0f;
  int t = 0;

  // 8-deep x prefetch slots: 3 v2f (6 floats) per slot, named, static indexing
  v2f x0a, x0b, x0c, x1a, x1b, x1c, x2a, x2b, x2c, x3a, x3b, x3c;
  v2f x4a, x4b, x4c, x5a, x5b, x5c, x6a, x6b, x6c, x7a, x7b, x7c;
  {
    auto ld = [&](int ti, v2f& A, v2f& B, v2f& C) {
      const int tc = (ti < len) ? ti : (len - 1);
      const v2f* p = (const v2f*)(xb + (size_t)tc * 6);
      A = p[0]; B = p[1]; C = p[2];
    };
    ld(0, x0a, x0b, x0c); ld(1, x1a, x1b, x1c);
    ld(2, x2a, x2b, x2c); ld(3, x3a, x3b, x3c);
    ld(4, x4a, x4b, x4c); ld(5, x5a, x5b, x5c);
    ld(6, x6a, x6b, x6c); ld(7, x7a, x7b, x7c);
  }

  // flush with fused FC: steps [base, base+cnt) -> out[base+i][o_]
  auto flush = [&](int base, int cnt) {
    const int i = l & 31;
    if (i < cnt) {
      const float4* hp = (const float4*)(&hring[(base >> 5) & 1][i][0]);
      float acc = 0.f;
#pragma unroll
      for (int qq = 0; qq < 8; ++qq) {
        const float4 hv = hp[qq], w = fcw4[qq];
        acc += hv.x * w.x + hv.y * w.y + hv.z * w.z + hv.w * w.w;
      }
      ob[(base + i) * 2 + o_] = acc + fcb_;
    }
  };

  auto step = [&](v2f& XA, v2f& XB, v2f& XC) {
    // x-side gate contributions (off-spine: inputs prefetched 8 steps ago)
    float xr_ = br, xz_ = bz, xn_ = bxn;
    {
      const float c0 = XA[0], c1 = XA[1], c2 = XB[0], c3 = XB[1],
                  c4 = XC[0], c5 = XC[1];
      xr_ = fmaf(wxr[0], c0, xr_); xr_ = fmaf(wxr[1], c1, xr_);
      xr_ = fmaf(wxr[2], c2, xr_); xr_ = fmaf(wxr[3], c3, xr_);
      xr_ = fmaf(wxr[4], c4, xr_); xr_ = fmaf(wxr[5], c5, xr_);
      xz_ = fmaf(wxz[0], c0, xz_); xz_ = fmaf(wxz[1], c1, xz_);
      xz_ = fmaf(wxz[2], c2, xz_); xz_ = fmaf(wxz[3], c3, xz_);
      xz_ = fmaf(wxz[4], c4, xz_); xz_ = fmaf(wxz[5], c5, xz_);
      xn_ = fmaf(wxn[0], c0, xn_); xn_ = fmaf(wxn[1], c1, xn_);
      xn_ = fmaf(wxn[2], c2, xn_); xn_ = fmaf(wxn[3], c3, xn_);
      xn_ = fmaf(wxn[4], c4, xn_); xn_ = fmaf(wxn[5], c5, xn_);
    }
    // refill this slot for t+8 (8 steps of latency slack)
    {
      const int tp = (t + 8 < len) ? (t + 8) : (len - 1);
      const v2f* p = (const v2f*)(xb + (size_t)tp * 6);
      XA = p[0]; XB = p[1]; XC = p[2];
    }

    // ---- A-frag rebuild: pure DPP/VALU, all within this lane's 16-row ----
    const int hi_ = __float_as_int(h);
    const int qa = dppmv<0x00>(hi_), qbv = dppmv<0x55>(hi_);
    const int qc = dppmv<0xAA>(hi_), qd = dppmv<0xFF>(hi_);
    const unsigned u0 = cvtpk(__int_as_float(qa), __int_as_float(qbv));
    const unsigned u1 = cvtpk(__int_as_float(qc), __int_as_float(qd));
    const int r4u0 = dppmv<0x124>((int)u0), r8u0 = dppmv<0x128>((int)u0),
              r12u0 = dppmv<0x12C>((int)u0);
    const int r4u1 = dppmv<0x124>((int)u1), r8u1 = dppmv<0x128>((int)u1),
              r12u1 = dppmv<0x12C>((int)u1);
    const unsigned d0 = s0b ? (s0a ? (unsigned)r12u0 : (unsigned)r8u0)
                            : (s0a ? (unsigned)r4u0 : u0);
    const unsigned d1 = s0b ? (s0a ? (unsigned)r12u1 : (unsigned)r8u1)
                            : (s0a ? (unsigned)r4u1 : u1);
    const unsigned d2 = s1b ? (s1a ? (unsigned)r12u0 : (unsigned)r8u0)
                            : (s1a ? (unsigned)r4u0 : u0);
    const unsigned d3 = s1b ? (s1a ? (unsigned)r12u1 : (unsigned)r8u1)
                            : (s1a ? (unsigned)r4u1 : u1);
    const v8bf ha = frag_from(d0, d1, d2, d3);

    // 6 independent MFMAs: full K=32 dot per gate-half
    const v4f yr0 = __builtin_amdgcn_mfma_f32_16x16x32_bf16(ha, fR0, zero4, 0, 0, 0);
    const v4f yr1 = __builtin_amdgcn_mfma_f32_16x16x32_bf16(ha, fR1, zero4, 0, 0, 0);
    const v4f yz0 = __builtin_amdgcn_mfma_f32_16x16x32_bf16(ha, fZ0, zero4, 0, 0, 0);
    const v4f yz1 = __builtin_amdgcn_mfma_f32_16x16x32_bf16(ha, fZ1, zero4, 0, 0, 0);
    const v4f yn0 = __builtin_amdgcn_mfma_f32_16x16x32_bf16(ha, fN0, cn0, 0, 0, 0);
    const v4f yn1 = __builtin_amdgcn_mfma_f32_16x16x32_bf16(ha, fN1, cn1, 0, 0, 0);

    const float yr = hiSel ? yr1[0] : yr0[0];
    const float yz = hiSel ? yz1[0] : yz0[0];
    const float hn = hiSel ? yn1[0] : yn0[0];  // incl. bhn via C

    const float r_ = __builtin_amdgcn_rcpf(1.0f + fexp2(-(yr + xr_)));
    const float z_ = __builtin_amdgcn_rcpf(1.0f + fexp2(-(yz + xz_)));
    const float ap = fmaf(r_, hn, xn_);
    const float q0 = __builtin_amdgcn_rcpf(1.0f + fexp2(-ap));
    const float nn = fmaf(2.0f, q0, -1.0f);
    h = fmaf(z_, h - nn, nn);

    hring[(t >> 5) & 1][t & 31][j] = h;  // duplicate halves write same value
    if ((t & 31) == 31) flush(t - 31, 32);
    ++t;
  };

  while (t + 8 <= len) {
    step(x0a, x0b, x0c);
    step(x1a, x1b, x1c);
    step(x2a, x2b, x2c);
    step(x3a, x3b, x3c);
    step(x4a, x4b, x4c);
    step(x5a, x5b, x5c);
    step(x6a, x6b, x6c);
    step(x7a, x7b, x7c);
  }
  if (t < len) step(x0a, x0b, x0c);
  if (t < len) step(x1a, x1b, x1c);
  if (t < len) step(x2a, x2b, x2c);
  if (t < len) step(x3a, x3b, x3c);
  if (t < len) step(x4a, x4b, x4c);
  if (t < len) step(x5a, x5b, x5c);
  if (t < len) step(x6a, x6b, x6c);

  const int rem = len & 31;
  if (rem) flush(len - rem, rem);

  // t >= len: ys == 0 -> output is fc_b
  for (int idx2 = len * 2 + l; idx2 < TT * 2; idx2 += 64)
    ob[idx2] = (idx2 & 1) ? fb1 : fb0;
}

extern "C" void kernel_launch(void* const* d_in, const int* in_sizes, int n_in,
                              void* d_out, int out_size, void* d_ws, size_t ws_size,
                              hipStream_t stream) {
  const float* x       = (const float*)d_in[0];
  const int*   lengths = (const int*)d_in[1];
  const float* w_ih    = (const float*)d_in[2];
  const float* w_hh    = (const float*)d_in[3];
  const float* b_ih    = (const float*)d_in[4];
  const float* b_hh    = (const float*)d_in[5];
  const float* fc_w    = (const float*)d_in[6];
  const float* fc_b    = (const float*)d_in[7];
  float* outp = (float*)d_out;

  hipLaunchKernelGGL(gru_fused, dim3(BB), dim3(64), 0, stream,
                     x, lengths, w_ih, w_hh, b_ih, b_hh, fc_w, fc_b, outp);
}